// Round 3
// baseline (180.369 us; speedup 1.0000x reference)
//
#include <hip/hip_runtime.h>

#define NBINS 10
#define TPB 256
#define NCOPY 32
#define CSTR 17                     // 17*c mod 32 is a bank bijection
#define LDSN (NCOPY * CSTR)         // 544 floats = 2176 B

__global__ void uce_zero(float* __restrict__ acc) {
    int i = threadIdx.x;
    if (i < NBINS) acc[i] = 0.0f;
}

// UCE = (1/n) * sum_b | sum_{i in bin b} (u_i - e_i) |   (count cancels exactly)
__global__ __launch_bounds__(TPB) void uce_hist(const float* __restrict__ up,
                                                const float* __restrict__ ep,
                                                float* __restrict__ acc, int n4) {
    __shared__ float h[LDSN];
    int tid = threadIdx.x;
    for (int i = tid; i < LDSN; i += TPB) h[i] = 0.0f;
    __syncthreads();

    int cbase = (tid & (NCOPY - 1)) * CSTR;   // private-ish copy per lane-pair

    const float4* __restrict__ u4 = (const float4*)up;
    const float4* __restrict__ e4 = (const float4*)ep;
    int T = gridDim.x * TPB;
#pragma unroll 4
    for (int i = blockIdx.x * TPB + tid; i < n4; i += T) {
        float4 uu = u4[i];
        float4 ee = e4[i];
        float us[4] = {uu.x, uu.y, uu.z, uu.w};
        float es[4] = {ee.x, ee.y, ee.z, ee.w};
#pragma unroll
        for (int k = 0; k < 4; ++k) {
            float u = us[k], e = es[k];
            // FROZEN binning (bit-exact vs reference, absmax 0.0 in R0/R1):
            // bin i iff fl(i*0.1f) < u <= fl((i+1)*0.1f)
            int g = (int)(u * 10.0f);
            g = g > 9 ? 9 : g;
            float gf = (float)g;
            float lo = gf * 0.1f;
            float hi = (gf + 1.0f) * 0.1f;     // == (float)(g+1)*0.1f exactly
            g += (u > hi) ? 1 : 0;             // conditions mutually exclusive
            g -= (u <= lo) ? 1 : 0;            // u<=0 -> -1; u>1.0 -> 10
            bool valid = ((unsigned)g <= 9u);
            float d = valid ? (u - e) : 0.0f;  // invalid adds 0.0
            int ga = g & 15;                   // -1->15, 10->10; max idx 542 < 544
            atomicAdd(&h[cbase + ga], d);      // ds_add_f32, no return -> no stall
        }
    }
    __syncthreads();

    // Block reduce: thread t (<10) sums its bin across the 32 copies.
    if (tid < NBINS) {
        float s = 0.0f;
#pragma unroll
        for (int c = 0; c < NCOPY; ++c) s += h[c * CSTR + tid];
        atomicAdd(&acc[tid], s);
    }
}

__global__ void uce_final(const float* __restrict__ acc, float* __restrict__ out,
                          float inv_n) {
    if (threadIdx.x == 0 && blockIdx.x == 0) {
        float uce = 0.0f;
#pragma unroll
        for (int b = 0; b < NBINS; ++b) uce += fabsf(acc[b]);
        out[0] = uce * inv_n;
    }
}

extern "C" void kernel_launch(void* const* d_in, const int* in_sizes, int n_in,
                              void* d_out, int out_size, void* d_ws, size_t ws_size,
                              hipStream_t stream) {
    const float* u = (const float*)d_in[0];
    const float* e = (const float*)d_in[1];
    float* acc = (float*)d_ws;
    float* out = (float*)d_out;
    int n = in_sizes[0];
    int n4 = n >> 2;

    uce_zero<<<1, 64, 0, stream>>>(acc);
    uce_hist<<<2048, TPB, 0, stream>>>(u, e, acc, n4);  // 8 blocks/CU, 32 waves/CU
    uce_final<<<1, 64, 0, stream>>>(acc, out, 1.0f / (float)n);
}

// Round 4
// 51.414 us; speedup vs baseline: 3.5082x; 3.5082x over previous
//
#include <hip/hip_runtime.h>

#define NBINS 10
#define TPB 256
#define NCOPY 32
#define CSTR 17                      // 17*c mod 32 is a bank bijection
#define LDSN (NCOPY * CSTR)          // 544 ints
#define SCALE 1048576.0f             // 2^20 fixed-point scale
#define INV_SCALE (1.0f / 1048576.0f)

// Pass 1: histogram of fixed-point d = u-e into per-block LDS (int, native
// ds_add_u32 fire-and-forget atomics), per-block float partials -> part[].
__global__ __launch_bounds__(TPB) void uce_hist(const float* __restrict__ up,
                                                const float* __restrict__ ep,
                                                float* __restrict__ part, int n4) {
    __shared__ int h[LDSN];
    int tid = threadIdx.x;
    for (int i = tid; i < LDSN; i += TPB) h[i] = 0;
    __syncthreads();

    int cbase = (tid & (NCOPY - 1)) * CSTR;

    auto proc1 = [&](float u, float e) {
        // FROZEN binning (bit-exact vs reference, absmax 0.0 in R0/R1/R2):
        // bin i iff fl(i*0.1f) < u <= fl((i+1)*0.1f)
        int g = (int)(u * 10.0f);
        g = g > 9 ? 9 : g;
        float gf = (float)g;
        float lo = gf * 0.1f;
        float hi = (gf + 1.0f) * 0.1f;
        g += (u > hi) ? 1 : 0;             // mutually exclusive fixups
        g -= (u <= lo) ? 1 : 0;            // u<=0 -> -1; u>1 -> 10
        int slot = g & 15;                 // -1->15, 10->10: scratch, never read
        int v = (int)rintf((u - e) * SCALE);
        atomicAdd(&h[cbase + slot], v);    // ds_add_u32, no return -> no stall
    };
    auto proc4 = [&](float4 uu, float4 ee) {
        proc1(uu.x, ee.x); proc1(uu.y, ee.y);
        proc1(uu.z, ee.z); proc1(uu.w, ee.w);
    };

    const float4* __restrict__ u4 = (const float4*)up;
    const float4* __restrict__ e4 = (const float4*)ep;
    int base = blockIdx.x * TPB + tid;
    int T = gridDim.x * TPB;
    int nb = n4 / (4 * T);               // full 8-load batches (exact for N=2^25)

    for (int it = 0; it < nb; ++it) {
        int i0 = base + it * 4 * T;
        // 8 independent 16B loads in flight (128 B/lane) before any use
        float4 ua = u4[i0], ub = u4[i0 + T], uc = u4[i0 + 2 * T], ud = u4[i0 + 3 * T];
        float4 ea = e4[i0], eb = e4[i0 + T], ec = e4[i0 + 2 * T], ed = e4[i0 + 3 * T];
        proc4(ua, ea); proc4(ub, eb); proc4(uc, ec); proc4(ud, ed);
    }
    for (int i = base + nb * 4 * T; i < n4; i += T) {   // tail (empty at N=2^25)
        proc4(u4[i], e4[i]);
    }
    __syncthreads();

    if (tid < NBINS) {
        int s = 0;
#pragma unroll
        for (int c = 0; c < NCOPY; ++c) s += h[c * CSTR + tid];
        part[blockIdx.x * NBINS + tid] = (float)s * INV_SCALE;
    }
}

// Pass 2: reduce per-block partials, UCE = (1/n) * sum_b |S_b|
__global__ __launch_bounds__(TPB) void uce_final(const float* __restrict__ part,
                                                 float* __restrict__ out,
                                                 int nblocks, float inv_n) {
    float s[NBINS];
#pragma unroll
    for (int b = 0; b < NBINS; ++b) s[b] = 0.0f;
    int tid = threadIdx.x;
    for (int j = tid; j < nblocks; j += TPB) {
        const float* p = part + j * NBINS;
#pragma unroll
        for (int b = 0; b < NBINS; ++b) s[b] += p[b];
    }
#pragma unroll
    for (int b = 0; b < NBINS; ++b) {
#pragma unroll
        for (int off = 32; off > 0; off >>= 1) s[b] += __shfl_down(s[b], off, 64);
    }
    __shared__ float sm[4][NBINS];
    int w = tid >> 6, lane = tid & 63;
    if (lane == 0) {
#pragma unroll
        for (int b = 0; b < NBINS; ++b) sm[w][b] = s[b];
    }
    __syncthreads();
    if (tid == 0) {
        float uce = 0.0f;
#pragma unroll
        for (int b = 0; b < NBINS; ++b) {
            float t = sm[0][b] + sm[1][b] + sm[2][b] + sm[3][b];
            uce += fabsf(t);
        }
        out[0] = uce * inv_n;
    }
}

extern "C" void kernel_launch(void* const* d_in, const int* in_sizes, int n_in,
                              void* d_out, int out_size, void* d_ws, size_t ws_size,
                              hipStream_t stream) {
    const float* u = (const float*)d_in[0];
    const float* e = (const float*)d_in[1];
    float* part = (float*)d_ws;          // 2048*10 floats = 80 KB scratch
    float* out = (float*)d_out;
    int n = in_sizes[0];
    int n4 = n >> 2;
    const int NB = 2048;                 // 8 blocks/CU, 32 waves/CU

    uce_hist<<<NB, TPB, 0, stream>>>(u, e, part, n4);
    uce_final<<<1, TPB, 0, stream>>>(part, out, NB, 1.0f / (float)n);
}